// Round 4
// baseline (419.229 us; speedup 1.0000x reference)
//
#include <hip/hip_runtime.h>

// VectorQuantizer, bit-replicating the harness's numpy fp32 reference.
// x [64,64,64,64] f32 -> flat [N=262144, D=64]; emb [D=64, K=512].
// out = concat(quantized_st flat [16777216], loss [1]) as f32.
//
// numpy semantics replicated exactly (all chains order-preserved):
//   sim[i,k]  = sequential fmaf chain over d=0..63
//   z2[i]     = numpy pairwise_sum(n=64): 8 accs, combined pairwise
//   e2[k]     = sequential sum over d ascending
//   dist      = fl(fl(z2+e2[k]) - 2*sim); argmin strict <, first wins
//   out       = fl(x + fl(q - x))
//
// R4 change vs R3: R2/R3 had VGPR_Count=52 (<64!) + 158MB of extra HBM writes
// -> z[64] was in SCRATCH (d-loop pragma unroll not honored -> runtime index
// -> local memory, skill rule #20). All z accesses are now macro-expanded
// with LITERAL indices so SROA must scalarize z into registers.
//
// ws layout (bytes):
//   0      : float  e2[512]
//   4096   : float  et[512*64]   (transposed codebook, row-major per code)
//   135168 : double partials[1024]

#define NROWS 262144
#define D 64
#define K 512

#define WS_E2 0
#define WS_ET 4096
#define WS_PARTIALS 135168

// ---- K1: transpose codebook + numpy-order squared norms ----
__global__ void __launch_bounds__(512) vq_prep(const float* __restrict__ emb, char* ws) {
    float* e2 = (float*)(ws + WS_E2);
    float* et = (float*)(ws + WS_ET);
    int k = threadIdx.x;  // 512 threads, one code each
    float v0 = emb[k];
    et[k * D] = v0;
    float s = __fmul_rn(v0, v0);
    for (int d = 1; d < D; ++d) {
        float v = emb[d * K + k];
        et[k * D + d] = v;
        s = __fadd_rn(s, __fmul_rn(v, v));  // sequential over d (np axis-0 reduce)
    }
    e2[k] = s;
}

// ---- K2: np-exact distance + argmin + gather + loss partials ----
__global__ void __launch_bounds__(256, 2) vq_main(const float* __restrict__ x,
                                                  float* __restrict__ out, char* ws) {
    const float* et = (const float*)(ws + WS_ET);
    const float* e2 = (const float*)(ws + WS_E2);
    double* partials = (double*)(ws + WS_PARTIALS);

    const int n = blockIdx.x * 256 + threadIdx.x;

    float z[64];  // every access below uses a LITERAL index -> SROA to registers
    const float4* xr = (const float4*)(x + (size_t)n * D);
#define LQ(q) { float4 v = xr[q]; z[4*(q)] = v.x; z[4*(q)+1] = v.y; \
                z[4*(q)+2] = v.z; z[4*(q)+3] = v.w; }
    LQ(0) LQ(1) LQ(2) LQ(3) LQ(4) LQ(5) LQ(6) LQ(7)
    LQ(8) LQ(9) LQ(10) LQ(11) LQ(12) LQ(13) LQ(14) LQ(15)
#undef LQ

    // z2: numpy pairwise_sum over fl(z*z), n=64
    float r0 = __fmul_rn(z[0], z[0]), r1 = __fmul_rn(z[1], z[1]);
    float r2 = __fmul_rn(z[2], z[2]), r3 = __fmul_rn(z[3], z[3]);
    float r4 = __fmul_rn(z[4], z[4]), r5 = __fmul_rn(z[5], z[5]);
    float r6 = __fmul_rn(z[6], z[6]), r7 = __fmul_rn(z[7], z[7]);
#define ROW(i) \
    r0 = __fadd_rn(r0, __fmul_rn(z[(i)],   z[(i)]));   \
    r1 = __fadd_rn(r1, __fmul_rn(z[(i)+1], z[(i)+1])); \
    r2 = __fadd_rn(r2, __fmul_rn(z[(i)+2], z[(i)+2])); \
    r3 = __fadd_rn(r3, __fmul_rn(z[(i)+3], z[(i)+3])); \
    r4 = __fadd_rn(r4, __fmul_rn(z[(i)+4], z[(i)+4])); \
    r5 = __fadd_rn(r5, __fmul_rn(z[(i)+5], z[(i)+5])); \
    r6 = __fadd_rn(r6, __fmul_rn(z[(i)+6], z[(i)+6])); \
    r7 = __fadd_rn(r7, __fmul_rn(z[(i)+7], z[(i)+7]));
    ROW(8) ROW(16) ROW(24) ROW(32) ROW(40) ROW(48) ROW(56)
#undef ROW
    float z2 = __fadd_rn(__fadd_rn(__fadd_rn(r0, r1), __fadd_rn(r2, r3)),
                         __fadd_rn(__fadd_rn(r4, r5), __fadd_rn(r6, r7)));

    // argmin over np-exact dist; 4 codes/iter = 4 independent FMA chains.
    // Codebook reads are wave-uniform -> scalar loads (lgkm pipe, not VALU).
    float best = 3.4e38f;
    int kb = 0;
    for (int k = 0; k < K; k += 4) {
        const float* ep = et + k * D;
        float a0 = 0.f, a1 = 0.f, a2 = 0.f, a3 = 0.f;
#define STEP(d) \
        a0 = fmaf(z[d], ep[d],           a0); \
        a1 = fmaf(z[d], ep[64  + (d)],   a1); \
        a2 = fmaf(z[d], ep[128 + (d)],   a2); \
        a3 = fmaf(z[d], ep[192 + (d)],   a3);
#define STEP8(d) STEP(d) STEP((d)+1) STEP((d)+2) STEP((d)+3) \
                 STEP((d)+4) STEP((d)+5) STEP((d)+6) STEP((d)+7)
        STEP8(0) STEP8(8) STEP8(16) STEP8(24) STEP8(32) STEP8(40) STEP8(48) STEP8(56)
#undef STEP8
#undef STEP
        float d0 = __fsub_rn(__fadd_rn(z2, e2[k]),     __fmul_rn(2.0f, a0));
        float d1 = __fsub_rn(__fadd_rn(z2, e2[k + 1]), __fmul_rn(2.0f, a1));
        float d2 = __fsub_rn(__fadd_rn(z2, e2[k + 2]), __fmul_rn(2.0f, a2));
        float d3 = __fsub_rn(__fadd_rn(z2, e2[k + 3]), __fmul_rn(2.0f, a3));
        if (d0 < best) { best = d0; kb = k; }       // strict <: first occurrence wins
        if (d1 < best) { best = d1; kb = k + 1; }
        if (d2 < best) { best = d2; kb = k + 2; }
        if (d3 < best) { best = d3; kb = k + 3; }
    }

    // gather winning code; out = fl(x + fl(q - x)); loss partial in fp64
    const float4* cq = (const float4*)(et + (size_t)kb * D);
    float4* outr = (float4*)(out + (size_t)n * D);
    double rs = 0.0;
#define OUTQ(g) { \
        float4 e4 = cq[g]; float4 o; \
        float d0 = __fsub_rn(e4.x, z[4*(g)]); \
        float d1 = __fsub_rn(e4.y, z[4*(g)+1]); \
        float d2 = __fsub_rn(e4.z, z[4*(g)+2]); \
        float d3 = __fsub_rn(e4.w, z[4*(g)+3]); \
        o.x = __fadd_rn(z[4*(g)],   d0); \
        o.y = __fadd_rn(z[4*(g)+1], d1); \
        o.z = __fadd_rn(z[4*(g)+2], d2); \
        o.w = __fadd_rn(z[4*(g)+3], d3); \
        outr[g] = o; \
        rs += (double)__fmul_rn(d0, d0) + (double)__fmul_rn(d1, d1) + \
              (double)__fmul_rn(d2, d2) + (double)__fmul_rn(d3, d3); }
    OUTQ(0) OUTQ(1) OUTQ(2) OUTQ(3) OUTQ(4) OUTQ(5) OUTQ(6) OUTQ(7)
    OUTQ(8) OUTQ(9) OUTQ(10) OUTQ(11) OUTQ(12) OUTQ(13) OUTQ(14) OUTQ(15)
#undef OUTQ

    __shared__ double red[256];
    red[threadIdx.x] = rs;
    __syncthreads();
    for (int s = 128; s > 0; s >>= 1) {
        if (threadIdx.x < s) red[threadIdx.x] += red[threadIdx.x + s];
        __syncthreads();
    }
    if (threadIdx.x == 0) partials[blockIdx.x] = red[0];
}

// ---- K3: finalize loss ----
__global__ void __launch_bounds__(256) vq_finalize(float* __restrict__ out, char* ws) {
    const double* partials = (const double*)(ws + WS_PARTIALS);
    __shared__ double red[256];
    double s = partials[threadIdx.x] + partials[threadIdx.x + 256] +
               partials[threadIdx.x + 512] + partials[threadIdx.x + 768];
    red[threadIdx.x] = s;
    __syncthreads();
    for (int st = 128; st > 0; st >>= 1) {
        if (threadIdx.x < st) red[threadIdx.x] += red[threadIdx.x + st];
        __syncthreads();
    }
    if (threadIdx.x == 0) {
        out[16777216] = (float)(1.25 * red[0] / 16777216.0);
    }
}

extern "C" void kernel_launch(void* const* d_in, const int* in_sizes, int n_in,
                              void* d_out, int out_size, void* d_ws, size_t ws_size,
                              hipStream_t stream) {
    const float* x   = (const float*)d_in[0];
    const float* emb = (const float*)d_in[1];
    float* out = (float*)d_out;
    char* ws = (char*)d_ws;

    vq_prep<<<1, 512, 0, stream>>>(emb, ws);
    vq_main<<<NROWS / 256, 256, 0, stream>>>(x, out, ws);
    vq_finalize<<<1, 256, 0, stream>>>(out, ws);
}